// Round 4
// baseline (229.905 us; speedup 1.0000x reference)
//
#include <hip/hip_runtime.h>

// QKVAttention: qkv [8, 3072, 1024] fp32 -> out [8, 1024, 1024] fp32
// Prepass: K (transpose+swizzle) and V (convert+swizzle) to fp16 ws.
// Attn: 512-thread blocks (8 waves x 32 t-rows), t-tile 256, Q fused via
// one-time LDS-transpose prologue. 4-buffer K/V pipeline: ONE barrier per
// 128 s (2 tiles), two independent QK->exp->PV chains per phase for ILP,
// prefetch 2 tiles ahead via global_load_lds. PV uses mfma_16x16x16 so the
// QK C-fragment feeds PV's A-operand directly in registers (no P LDS).

typedef __attribute__((ext_vector_type(8))) _Float16 f16x8;
typedef __attribute__((ext_vector_type(4))) _Float16 f16x4;
typedef __attribute__((ext_vector_type(4))) float f32x4;

#define MAT_HALVES 8388608   // 16 MB per matrix (128 heads * 64 * 1024 halves)
#define WS_BYTES   33554432  // K + V fp16

#define ASYNC16(g, l) __builtin_amdgcn_global_load_lds(                    \
    (__attribute__((address_space(1))) void*)(void*)(g),                   \
    (__attribute__((address_space(3))) void*)(void*)(l), 16, 0, 0)

// ---------------- Pre-pass: K transpose + V convert, fp32 -> fp16 ------------
// Kt [head][s][64c], chunk c' = cb ^ (s&7)
// Vh [head][c][1024s], within each 64-s tile chunk s' = sb ^ (c&7)
__global__ __launch_bounds__(256) void prepass_kv(
    const float* __restrict__ qkv, _Float16* __restrict__ ws) {
    __shared__ float ft[64][68];
    const int tid = threadIdx.x;
    const int bid = blockIdx.x;       // 4096 = 2 mats * 128 heads * 16 blocks
    const int mat = bid >> 11;        // 0 K, 1 V
    const int idx = bid & 2047;
    const int head = idx >> 4;
    const int blk  = idx & 15;
    const int b = head >> 4, h = head & 15;
    const float* src = qkv + (size_t)b * 3072 * 1024
                           + (size_t)((1 + mat) * 1024 + h * 64) * 1024;
    const int s0 = blk * 64;
    if (mat == 0) {
#pragma unroll
        for (int i = 0; i < 4; ++i) {
            const int c = i * 16 + (tid >> 4);
            const int s = (tid & 15) * 4;
            const float4 v = *(const float4*)(src + (size_t)c * 1024 + s0 + s);
            ft[s + 0][c] = v.x;
            ft[s + 1][c] = v.y;
            ft[s + 2][c] = v.z;
            ft[s + 3][c] = v.w;
        }
        __syncthreads();
        _Float16* dst = ws + (size_t)head * 65536 + (size_t)s0 * 64;
#pragma unroll
        for (int r = 0; r < 2; ++r) {
            const int g = r * 256 + tid;
            const int t = g >> 3, cb = g & 7;
            const float4 a = *(const float4*)&ft[t][cb * 8];
            const float4 bq = *(const float4*)&ft[t][cb * 8 + 4];
            f16x8 o = { (_Float16)a.x,  (_Float16)a.y,  (_Float16)a.z,  (_Float16)a.w,
                        (_Float16)bq.x, (_Float16)bq.y, (_Float16)bq.z, (_Float16)bq.w };
            *(f16x8*)(dst + (size_t)t * 64 + (size_t)(cb ^ (t & 7)) * 8) = o;
        }
    } else {
        _Float16* dst = ws + (size_t)MAT_HALVES + (size_t)head * 65536;
#pragma unroll
        for (int i = 0; i < 4; ++i) {
            const int c = i * 16 + (tid >> 4);
            const int s = (tid & 15) * 4;
            const float4 v = *(const float4*)(src + (size_t)c * 1024 + s0 + s);
            f16x4 o = { (_Float16)v.x, (_Float16)v.y, (_Float16)v.z, (_Float16)v.w };
            const int sb = s >> 3, pos = s & 7;
            *(f16x4*)(dst + (size_t)c * 1024 + s0 + (size_t)((sb ^ (c & 7)) * 8 + pos)) = o;
        }
    }
}

// ---------------- Main flash kernel: 8 waves, 4-buffer pipeline --------------
__launch_bounds__(512, 4)
__global__ void attn_kernel(const float* __restrict__ qkv,
                            const _Float16* __restrict__ ws,
                            float* __restrict__ out) {
    // kv[buf]: K [64 s][64 c] at halves 0..4095, V [64 c][64 s] at 4096..8191.
    // Tile si lives in buf (si+2)&3. ft overlays kv[0..1] (prologue only;
    // tiles 0,1 prefetch into kv[2],kv[3] so no clash).
    __shared__ __align__(16) union SM {
        _Float16 kv[4][8192];   // 64 KB
        float ft[64][68];       // 17.4 KB (prologue only)
    } sm;

    const int tid  = threadIdx.x;
    const int wv   = tid >> 6;        // 0..7
    const int lane = tid & 63;
    const int li   = lane & 15;
    const int quad = lane >> 4;

    const int bid  = blockIdx.x;
    const int head = (bid >> 5) * 8 + (bid & 7);  // head's 4 t-tiles share an XCD
    const int tt   = (bid >> 3) & 3;
    const int t0   = tt * 256;

    const int b = head >> 4, h = head & 15;
    const float* qsrc = qkv + (size_t)b * 3072 * 1024 + (size_t)(h * 64) * 1024;
    const _Float16* kt = ws + (size_t)head * 65536;
    const _Float16* vh = ws + (size_t)MAT_HALVES + (size_t)head * 65536;

    // ---- Prefetch tiles 0,1 into kv[2],kv[3] (latency hides under Q work) ----
#pragma unroll
    for (int u = 0; u < 2; ++u) {
        const int s0 = u * 64;
        ASYNC16(kt + (size_t)s0 * 64 + (size_t)tid * 8, &sm.kv[2 + u][tid * 8]);
        ASYNC16(vh + (size_t)(tid >> 3) * 1024 + s0 + (size_t)(tid & 7) * 8,
                &sm.kv[2 + u][4096 + tid * 8]);
    }

    // ---- Q prologue: preload to regs, then 4 LDS-transpose rounds ----
    const float qscale = 0.125f * 1.44269504f;
    const int ci = tid >> 4;          // 0..31
    const int tq = (tid & 15) * 4;
    float4 qv[4][2];
#pragma unroll
    for (int ct = 0; ct < 4; ++ct)
#pragma unroll
        for (int i = 0; i < 2; ++i) {
            const int c = i * 32 + ci;
            qv[ct][i] = *(const float4*)(qsrc + (size_t)c * 1024 + t0 + ct * 64 + tq);
        }
    f16x8 bqf[2][2];
#pragma unroll
    for (int ct = 0; ct < 4; ++ct) {
#pragma unroll
        for (int i = 0; i < 2; ++i) {
            const int c = i * 32 + ci;
            sm.ft[tq + 0][c] = qv[ct][i].x * qscale;
            sm.ft[tq + 1][c] = qv[ct][i].y * qscale;
            sm.ft[tq + 2][c] = qv[ct][i].z * qscale;
            sm.ft[tq + 3][c] = qv[ct][i].w * qscale;
        }
        __syncthreads();
        if ((wv >> 1) == ct) {
#pragma unroll
            for (int sub = 0; sub < 2; ++sub) {
                const int tl = (wv & 1) * 32 + sub * 16 + li;
#pragma unroll
                for (int kk = 0; kk < 2; ++kk) {
                    const int c0 = (kk * 4 + quad) * 8;
                    const float4 a  = *(const float4*)&sm.ft[tl][c0];
                    const float4 b2 = *(const float4*)&sm.ft[tl][c0 + 4];
                    bqf[sub][kk] = f16x8{ (_Float16)a.x,  (_Float16)a.y,
                                          (_Float16)a.z,  (_Float16)a.w,
                                          (_Float16)b2.x, (_Float16)b2.y,
                                          (_Float16)b2.z, (_Float16)b2.w };
                }
            }
        }
        __syncthreads();
    }

    f32x4 accz[2][4] = {};       // [sub][nc]
    float psum[2] = {};

    // ---- Main loop: 8 phases x 2 s-tiles, 1 barrier per phase ----
    for (int p = 0; p < 8; ++p) {
        __syncthreads();  // bufs for tiles 2p,2p+1 drained; prior-phase reads done
        if (p < 7) {
#pragma unroll
            for (int u = 0; u < 2; ++u) {
                const int sn  = 2 * p + 2 + u;
                const int s0n = sn * 64;
                const int nb  = (sn + 2) & 3;
                ASYNC16(kt + (size_t)s0n * 64 + (size_t)tid * 8, &sm.kv[nb][tid * 8]);
                ASYNC16(vh + (size_t)(tid >> 3) * 1024 + s0n + (size_t)(tid & 7) * 8,
                        &sm.kv[nb][4096 + tid * 8]);
            }
        }
#pragma unroll
        for (int u = 0; u < 2; ++u) {
            const int si = 2 * p + u;
            const _Float16* Kl = &sm.kv[(si + 2) & 3][0];
            const _Float16* Vl = &sm.kv[(si + 2) & 3][4096];

#pragma unroll
            for (int ns = 0; ns < 4; ++ns) {
                // S^T = K Q^T for this 16-s strip (k=64 via 2 x mfma 16x16x32)
                f16x8 ak[2];
#pragma unroll
                for (int kk = 0; kk < 2; ++kk) {
                    const int cb = (kk * 4 + quad) ^ (li & 7);
                    ak[kk] = *(const f16x8*)&Kl[(ns * 16 + li) * 64 + cb * 8];
                }
                f16x4 pk[2];
#pragma unroll
                for (int sub = 0; sub < 2; ++sub) {
                    f32x4 st = {};
                    st = __builtin_amdgcn_mfma_f32_16x16x32_f16(ak[0], bqf[sub][0], st, 0, 0, 0);
                    st = __builtin_amdgcn_mfma_f32_16x16x32_f16(ak[1], bqf[sub][1], st, 0, 0, 0);
                    const float p0 = __builtin_amdgcn_exp2f(st[0]);
                    const float p1 = __builtin_amdgcn_exp2f(st[1]);
                    const float p2 = __builtin_amdgcn_exp2f(st[2]);
                    const float p3 = __builtin_amdgcn_exp2f(st[3]);
                    psum[sub] += (p0 + p1) + (p2 + p3);
                    pk[sub] = f16x4{ (_Float16)p0, (_Float16)p1,
                                     (_Float16)p2, (_Float16)p3 };
                }
                // Z^T += P V^T for this strip: pk IS the 16x16x16 A-operand.
                const int sb  = 2 * ns + (quad >> 1);
                const int pos = (quad & 1) * 4;
#pragma unroll
                for (int nc = 0; nc < 4; ++nc) {
                    const int c = nc * 16 + li;
                    f16x4 bv = *(const f16x4*)&Vl[c * 64 + ((sb ^ (c & 7)) << 3) + pos];
                    accz[0][nc] = __builtin_amdgcn_mfma_f32_16x16x16f16(
                        pk[0], bv, accz[0][nc], 0, 0, 0);
                    accz[1][nc] = __builtin_amdgcn_mfma_f32_16x16x16f16(
                        pk[1], bv, accz[1][nc], 0, 0, 0);
                }
            }
        }
    }

    // ---- Denominators: cross-quad reduce + redistribute ----
    float rl[2][4];
#pragma unroll
    for (int sub = 0; sub < 2; ++sub) {
        float s = psum[sub];
        s += __shfl_xor(s, 16);
        s += __shfl_xor(s, 32);
#pragma unroll
        for (int r = 0; r < 4; ++r)
            rl[sub][r] = 1.0f / __shfl(s, quad * 4 + r);
    }

    // ---- Store: D^T rows contiguous in t -> direct float4 stores ----
    float* obase = out + (size_t)b * 1024 * 1024
                       + (size_t)(h * 64) * 1024 + t0;
#pragma unroll
    for (int sub = 0; sub < 2; ++sub)
#pragma unroll
        for (int nc = 0; nc < 4; ++nc) {
            const int c = nc * 16 + li;
            const int t = wv * 32 + sub * 16 + quad * 4;
            f32x4 z = accz[sub][nc];
            float4 o = { z[0] * rl[sub][0], z[1] * rl[sub][1],
                         z[2] * rl[sub][2], z[3] * rl[sub][3] };
            *(float4*)(obase + (size_t)c * 1024 + t) = o;
        }
}

// ---------------- Fallback (single-kernel path, ws too small) ----------------
struct S1fb {
    _Float16 K[64][72];
    _Float16 V[64][72];
    _Float16 P[128][72];
};
union SMemFb {
    S1fb s1;
    float zt[64][132];
};

__launch_bounds__(256, 4)
__global__ void qkv_attn_fallback(const float* __restrict__ qkv,
                                  float* __restrict__ out) {
    constexpr int L = 1024;
    __shared__ SMemFb sm;
    const int tid  = threadIdx.x;
    const int wv   = tid >> 6;
    const int lane = tid & 63;
    const int li   = lane & 15;
    const int quad = lane >> 4;
    const int bid  = blockIdx.x;
    const int head = (bid >> 6) * 8 + (bid & 7);
    const int tt   = (bid >> 3) & 7;
    const int b = head >> 4;
    const int h = head & 15;
    const float* qbase = qkv + (size_t)b * 3072 * L + (size_t)(h * 64) * L;
    const float* kbase = qbase + (size_t)1024 * L;
    const float* vbase = qbase + (size_t)2048 * L;
    float*       obase = out + (size_t)b * 1024 * L + (size_t)(h * 64) * L;
    const int t0 = tt * 128;
#pragma unroll
    for (int i = 0; i < 4; ++i) {
        const int c = i * 16 + (tid >> 4);
        const int t = (tid & 15) * 8;
        const float4 qa = *(const float4*)(qbase + (size_t)c * L + t0 + t);
        const float4 qb = *(const float4*)(qbase + (size_t)c * L + t0 + t + 4);
        sm.s1.P[t + 0][c] = (_Float16)(qa.x * 0.125f);
        sm.s1.P[t + 1][c] = (_Float16)(qa.y * 0.125f);
        sm.s1.P[t + 2][c] = (_Float16)(qa.z * 0.125f);
        sm.s1.P[t + 3][c] = (_Float16)(qa.w * 0.125f);
        sm.s1.P[t + 4][c] = (_Float16)(qb.x * 0.125f);
        sm.s1.P[t + 5][c] = (_Float16)(qb.y * 0.125f);
        sm.s1.P[t + 6][c] = (_Float16)(qb.z * 0.125f);
        sm.s1.P[t + 7][c] = (_Float16)(qb.w * 0.125f);
    }
    __syncthreads();
    f16x8 aq0[2], aq1[2];
#pragma unroll
    for (int kk = 0; kk < 2; ++kk) {
        aq0[kk] = *(const f16x8*)&sm.s1.P[wv * 32 + li][kk * 32 + quad * 8];
        aq1[kk] = *(const f16x8*)&sm.s1.P[wv * 32 + 16 + li][kk * 32 + quad * 8];
    }
    f32x4 accz0[4] = {}, accz1[4] = {};
    float psum0[4] = {}, psum1[4] = {};
    float4 kreg[4], vreg[4];
#pragma unroll
    for (int i = 0; i < 4; ++i) {
        const int c = i * 16 + (tid >> 4);
        const int s = (tid & 15) * 4;
        kreg[i] = *(const float4*)(kbase + (size_t)c * L + s);
        vreg[i] = *(const float4*)(vbase + (size_t)c * L + s);
    }
    for (int si = 0; si < 16; ++si) {
        __syncthreads();
#pragma unroll
        for (int i = 0; i < 4; ++i) {
            const int c = i * 16 + (tid >> 4);
            const int s = (tid & 15) * 4;
            sm.s1.K[s + 0][c] = (_Float16)kreg[i].x;
            sm.s1.K[s + 1][c] = (_Float16)kreg[i].y;
            sm.s1.K[s + 2][c] = (_Float16)kreg[i].z;
            sm.s1.K[s + 3][c] = (_Float16)kreg[i].w;
            f16x4 pv = { (_Float16)vreg[i].x, (_Float16)vreg[i].y,
                         (_Float16)vreg[i].z, (_Float16)vreg[i].w };
            *(f16x4*)&sm.s1.V[c][s] = pv;
        }
        __syncthreads();
        if (si < 15) {
            const int s0n = (si + 1) * 64;
#pragma unroll
            for (int i = 0; i < 4; ++i) {
                const int c = i * 16 + (tid >> 4);
                const int s = (tid & 15) * 4;
                kreg[i] = *(const float4*)(kbase + (size_t)c * L + s0n + s);
                vreg[i] = *(const float4*)(vbase + (size_t)c * L + s0n + s);
            }
        }
#pragma unroll
        for (int nt = 0; nt < 4; ++nt) {
            f32x4 a0 = {}, a1 = {};
#pragma unroll
            for (int kk = 0; kk < 2; ++kk) {
                f16x8 bk = *(const f16x8*)&sm.s1.K[nt * 16 + li][kk * 32 + quad * 8];
                a0 = __builtin_amdgcn_mfma_f32_16x16x32_f16(aq0[kk], bk, a0, 0, 0, 0);
                a1 = __builtin_amdgcn_mfma_f32_16x16x32_f16(aq1[kk], bk, a1, 0, 0, 0);
            }
#pragma unroll
            for (int r = 0; r < 4; ++r) {
                const float p0 = __expf(a0[r]);
                const float p1 = __expf(a1[r]);
                psum0[r] += p0;
                psum1[r] += p1;
                sm.s1.P[wv * 32 + quad * 4 + r][nt * 16 + li] = (_Float16)p0;
                sm.s1.P[wv * 32 + 16 + quad * 4 + r][nt * 16 + li] = (_Float16)p1;
            }
        }
#pragma unroll
        for (int kk = 0; kk < 2; ++kk) {
            f16x8 ap0 = *(const f16x8*)&sm.s1.P[wv * 32 + li][kk * 32 + quad * 8];
            f16x8 ap1 = *(const f16x8*)&sm.s1.P[wv * 32 + 16 + li][kk * 32 + quad * 8];
#pragma unroll
            for (int nt = 0; nt < 4; ++nt) {
                f16x8 bv = *(const f16x8*)&sm.s1.V[nt * 16 + li][kk * 32 + quad * 8];
                accz0[nt] = __builtin_amdgcn_mfma_f32_16x16x32_f16(ap0, bv, accz0[nt], 0, 0, 0);
                accz1[nt] = __builtin_amdgcn_mfma_f32_16x16x32_f16(ap1, bv, accz1[nt], 0, 0, 0);
            }
        }
    }
    float rl0[4], rl1[4];
#pragma unroll
    for (int r = 0; r < 4; ++r) {
        float s0 = psum0[r], s1 = psum1[r];
        s0 += __shfl_xor(s0, 1); s0 += __shfl_xor(s0, 2);
        s0 += __shfl_xor(s0, 4); s0 += __shfl_xor(s0, 8);
        s1 += __shfl_xor(s1, 1); s1 += __shfl_xor(s1, 2);
        s1 += __shfl_xor(s1, 4); s1 += __shfl_xor(s1, 8);
        rl0[r] = 1.0f / s0;
        rl1[r] = 1.0f / s1;
    }
    __syncthreads();
#pragma unroll
    for (int nt = 0; nt < 4; ++nt)
#pragma unroll
        for (int r = 0; r < 4; ++r) {
            sm.zt[nt * 16 + li][wv * 32 + quad * 4 + r]      = accz0[nt][r] * rl0[r];
            sm.zt[nt * 16 + li][wv * 32 + 16 + quad * 4 + r] = accz1[nt][r] * rl1[r];
        }
    __syncthreads();
#pragma unroll
    for (int i = 0; i < 8; ++i) {
        const int c = i * 8 + (tid >> 5);
        const int t = (tid & 31) * 4;
        float4 o = { sm.zt[c][t], sm.zt[c][t + 1],
                     sm.zt[c][t + 2], sm.zt[c][t + 3] };
        *(float4*)(obase + (size_t)c * L + t0 + t) = o;
    }
}

extern "C" void kernel_launch(void* const* d_in, const int* in_sizes, int n_in,
                              void* d_out, int out_size, void* d_ws, size_t ws_size,
                              hipStream_t stream) {
    const float* qkv = (const float*)d_in[0];
    float* out = (float*)d_out;
    if (ws_size >= (size_t)WS_BYTES) {
        _Float16* ws = (_Float16*)d_ws;
        prepass_kv<<<4096, 256, 0, stream>>>(qkv, ws);
        // 128 heads x 4 t-tiles of 256; 512-thread blocks -> 2 blocks/CU, 16 waves
        attn_kernel<<<512, 512, 0, stream>>>(qkv, ws, out);
    } else {
        qkv_attn_fallback<<<1024, 256, 0, stream>>>(qkv, out);
    }
}

// Round 6
// 194.405 us; speedup vs baseline: 1.1826x; 1.1826x over previous
//
#include <hip/hip_runtime.h>

// QKVAttention: qkv [8, 3072, 1024] fp32 -> out [8, 1024, 1024] fp32
// Prepass: K (transpose+swizzle) and V (convert+swizzle) to fp16 ws.
// Attn: 512-thread blocks (8 waves x 32 t-rows), t-tile 256, Q fused via
// one-time LDS-transpose prologue (direct global reads - NO reg preload,
// round-4's qv preload caused scratch spill: WRITE_SIZE 33->95 MB).
// 4-buffer K/V pipeline: ONE barrier per 128 s (2 tiles), two independent
// QK->exp->PV chains per phase, prefetch 2 tiles ahead via global_load_lds.
// PV uses mfma_16x16x16 so the QK C-fragment feeds PV's A-operand directly
// in registers (no P LDS round-trip). s_setprio(1) around MFMA clusters.

typedef __attribute__((ext_vector_type(8))) _Float16 f16x8;
typedef __attribute__((ext_vector_type(4))) _Float16 f16x4;
typedef __attribute__((ext_vector_type(4))) float f32x4;

#define MAT_HALVES 8388608   // 16 MB per matrix (128 heads * 64 * 1024 halves)
#define WS_BYTES   33554432  // K + V fp16

#define ASYNC16(g, l) __builtin_amdgcn_global_load_lds(                    \
    (__attribute__((address_space(1))) void*)(void*)(g),                   \
    (__attribute__((address_space(3))) void*)(void*)(l), 16, 0, 0)

// ---------------- Pre-pass: K transpose + V convert, fp32 -> fp16 ------------
// Kt [head][s][64c], chunk c' = cb ^ (s&7)
// Vh [head][c][1024s], within each 64-s tile chunk s' = sb ^ (c&7)
__global__ __launch_bounds__(256) void prepass_kv(
    const float* __restrict__ qkv, _Float16* __restrict__ ws) {
    __shared__ float ft[64][68];
    const int tid = threadIdx.x;
    const int bid = blockIdx.x;       // 4096 = 2 mats * 128 heads * 16 blocks
    const int mat = bid >> 11;        // 0 K, 1 V
    const int idx = bid & 2047;
    const int head = idx >> 4;
    const int blk  = idx & 15;
    const int b = head >> 4, h = head & 15;
    const float* src = qkv + (size_t)b * 3072 * 1024
                           + (size_t)((1 + mat) * 1024 + h * 64) * 1024;
    const int s0 = blk * 64;
    if (mat == 0) {
#pragma unroll
        for (int i = 0; i < 4; ++i) {
            const int c = i * 16 + (tid >> 4);
            const int s = (tid & 15) * 4;
            const float4 v = *(const float4*)(src + (size_t)c * 1024 + s0 + s);
            ft[s + 0][c] = v.x;
            ft[s + 1][c] = v.y;
            ft[s + 2][c] = v.z;
            ft[s + 3][c] = v.w;
        }
        __syncthreads();
        _Float16* dst = ws + (size_t)head * 65536 + (size_t)s0 * 64;
#pragma unroll
        for (int r = 0; r < 2; ++r) {
            const int g = r * 256 + tid;
            const int t = g >> 3, cb = g & 7;
            const float4 a = *(const float4*)&ft[t][cb * 8];
            const float4 bq = *(const float4*)&ft[t][cb * 8 + 4];
            f16x8 o = { (_Float16)a.x,  (_Float16)a.y,  (_Float16)a.z,  (_Float16)a.w,
                        (_Float16)bq.x, (_Float16)bq.y, (_Float16)bq.z, (_Float16)bq.w };
            *(f16x8*)(dst + (size_t)t * 64 + (size_t)(cb ^ (t & 7)) * 8) = o;
        }
    } else {
        _Float16* dst = ws + (size_t)MAT_HALVES + (size_t)head * 65536;
#pragma unroll
        for (int i = 0; i < 4; ++i) {
            const int c = i * 16 + (tid >> 4);
            const int s = (tid & 15) * 4;
            const float4 v = *(const float4*)(src + (size_t)c * 1024 + s0 + s);
            f16x4 o = { (_Float16)v.x, (_Float16)v.y, (_Float16)v.z, (_Float16)v.w };
            const int sb = s >> 3, pos = s & 7;
            *(f16x4*)(dst + (size_t)c * 1024 + s0 + (size_t)((sb ^ (c & 7)) * 8 + pos)) = o;
        }
    }
}

// ---------------- Main flash kernel: 8 waves, 4-buffer pipeline --------------
__launch_bounds__(512, 2)
__global__ void attn_kernel(const float* __restrict__ qkv,
                            const _Float16* __restrict__ ws,
                            float* __restrict__ out) {
    // kv[buf]: K [64 s][64 c] at halves 0..4095, V [64 c][64 s] at 4096..8191.
    // Tile si lives in buf (si+2)&3. ft overlays kv[0..1] (prologue only;
    // tiles 0,1 prefetch into kv[2],kv[3] so no clash).
    __shared__ __align__(16) union SM {
        _Float16 kv[4][8192];   // 64 KB
        float ft[64][68];       // 17.4 KB (prologue only)
    } sm;

    const int tid  = threadIdx.x;
    const int wv   = tid >> 6;        // 0..7
    const int lane = tid & 63;
    const int li   = lane & 15;
    const int quad = lane >> 4;

    const int bid  = blockIdx.x;
    const int head = (bid >> 5) * 8 + (bid & 7);  // head's 4 t-tiles share an XCD
    const int tt   = (bid >> 3) & 3;
    const int t0   = tt * 256;

    const int b = head >> 4, h = head & 15;
    const float* qsrc = qkv + (size_t)b * 3072 * 1024 + (size_t)(h * 64) * 1024;
    const _Float16* kt = ws + (size_t)head * 65536;
    const _Float16* vh = ws + (size_t)MAT_HALVES + (size_t)head * 65536;

    // ---- Prefetch tiles 0,1 into kv[2],kv[3] (latency hides under Q work) ----
#pragma unroll
    for (int u = 0; u < 2; ++u) {
        const int s0 = u * 64;
        ASYNC16(kt + (size_t)s0 * 64 + (size_t)tid * 8, &sm.kv[2 + u][tid * 8]);
        ASYNC16(vh + (size_t)(tid >> 3) * 1024 + s0 + (size_t)(tid & 7) * 8,
                &sm.kv[2 + u][4096 + tid * 8]);
    }

    // ---- Q prologue: 4 chunks of 64 t, fp32 LDS transpose -> bqf regs ----
    const float qscale = 0.125f * 1.44269504f;
    f16x8 bqf[2][2];
    {
        const int ci = tid >> 4;          // 0..31
        const int tq = (tid & 15) * 4;
        for (int ct = 0; ct < 4; ++ct) {
#pragma unroll
            for (int i = 0; i < 2; ++i) {
                const int c = i * 32 + ci;
                const float4 v = *(const float4*)(qsrc + (size_t)c * 1024 + t0 + ct * 64 + tq);
                sm.ft[tq + 0][c] = v.x * qscale;
                sm.ft[tq + 1][c] = v.y * qscale;
                sm.ft[tq + 2][c] = v.z * qscale;
                sm.ft[tq + 3][c] = v.w * qscale;
            }
            __syncthreads();
            if ((wv >> 1) == ct) {
#pragma unroll
                for (int sub = 0; sub < 2; ++sub) {
                    const int tl = (wv & 1) * 32 + sub * 16 + li;
#pragma unroll
                    for (int kk = 0; kk < 2; ++kk) {
                        const int c0 = (kk * 4 + quad) * 8;
                        const float4 a  = *(const float4*)&sm.ft[tl][c0];
                        const float4 b2 = *(const float4*)&sm.ft[tl][c0 + 4];
                        bqf[sub][kk] = f16x8{ (_Float16)a.x,  (_Float16)a.y,
                                              (_Float16)a.z,  (_Float16)a.w,
                                              (_Float16)b2.x, (_Float16)b2.y,
                                              (_Float16)b2.z, (_Float16)b2.w };
                    }
                }
            }
            __syncthreads();
        }
    }

    f32x4 accz[2][4] = {};       // [sub][nc]
    float psum[2] = {};

    // ---- Main loop: 8 phases x 2 s-tiles, 1 barrier per phase ----
    for (int p = 0; p < 8; ++p) {
        __syncthreads();  // bufs for tiles 2p,2p+1 drained; prior-phase reads done
        if (p < 7) {
#pragma unroll
            for (int u = 0; u < 2; ++u) {
                const int sn  = 2 * p + 2 + u;
                const int s0n = sn * 64;
                const int nb  = (sn + 2) & 3;
                ASYNC16(kt + (size_t)s0n * 64 + (size_t)tid * 8, &sm.kv[nb][tid * 8]);
                ASYNC16(vh + (size_t)(tid >> 3) * 1024 + s0n + (size_t)(tid & 7) * 8,
                        &sm.kv[nb][4096 + tid * 8]);
            }
        }
#pragma unroll
        for (int u = 0; u < 2; ++u) {
            const int si = 2 * p + u;
            const _Float16* Kl = &sm.kv[(si + 2) & 3][0];
            const _Float16* Vl = &sm.kv[(si + 2) & 3][4096];

            __builtin_amdgcn_s_setprio(1);
#pragma unroll
            for (int ns = 0; ns < 4; ++ns) {
                // S^T = K Q^T for this 16-s strip (k=64 via 2 x mfma 16x16x32)
                f16x8 ak[2];
#pragma unroll
                for (int kk = 0; kk < 2; ++kk) {
                    const int cb = (kk * 4 + quad) ^ (li & 7);
                    ak[kk] = *(const f16x8*)&Kl[(ns * 16 + li) * 64 + cb * 8];
                }
                f16x4 pk[2];
#pragma unroll
                for (int sub = 0; sub < 2; ++sub) {
                    f32x4 st = {};
                    st = __builtin_amdgcn_mfma_f32_16x16x32_f16(ak[0], bqf[sub][0], st, 0, 0, 0);
                    st = __builtin_amdgcn_mfma_f32_16x16x32_f16(ak[1], bqf[sub][1], st, 0, 0, 0);
                    const float p0 = __builtin_amdgcn_exp2f(st[0]);
                    const float p1 = __builtin_amdgcn_exp2f(st[1]);
                    const float p2 = __builtin_amdgcn_exp2f(st[2]);
                    const float p3 = __builtin_amdgcn_exp2f(st[3]);
                    psum[sub] += (p0 + p1) + (p2 + p3);
                    pk[sub] = f16x4{ (_Float16)p0, (_Float16)p1,
                                     (_Float16)p2, (_Float16)p3 };
                }
                // Z^T += P V^T for this strip: pk IS the 16x16x16 A-operand.
                const int sb  = 2 * ns + (quad >> 1);
                const int pos = (quad & 1) * 4;
#pragma unroll
                for (int nc = 0; nc < 4; ++nc) {
                    const int c = nc * 16 + li;
                    f16x4 bv = *(const f16x4*)&Vl[c * 64 + ((sb ^ (c & 7)) << 3) + pos];
                    accz[0][nc] = __builtin_amdgcn_mfma_f32_16x16x16f16(
                        pk[0], bv, accz[0][nc], 0, 0, 0);
                    accz[1][nc] = __builtin_amdgcn_mfma_f32_16x16x16f16(
                        pk[1], bv, accz[1][nc], 0, 0, 0);
                }
            }
            __builtin_amdgcn_s_setprio(0);
        }
    }

    // ---- Denominators: cross-quad reduce + redistribute ----
    float rl[2][4];
#pragma unroll
    for (int sub = 0; sub < 2; ++sub) {
        float s = psum[sub];
        s += __shfl_xor(s, 16);
        s += __shfl_xor(s, 32);
#pragma unroll
        for (int r = 0; r < 4; ++r)
            rl[sub][r] = 1.0f / __shfl(s, quad * 4 + r);
    }

    // ---- Store: D^T rows contiguous in t -> direct float4 stores ----
    float* obase = out + (size_t)b * 1024 * 1024
                       + (size_t)(h * 64) * 1024 + t0;
#pragma unroll
    for (int sub = 0; sub < 2; ++sub)
#pragma unroll
        for (int nc = 0; nc < 4; ++nc) {
            const int c = nc * 16 + li;
            const int t = wv * 32 + sub * 16 + quad * 4;
            f32x4 z = accz[sub][nc];
            float4 o = { z[0] * rl[sub][0], z[1] * rl[sub][1],
                         z[2] * rl[sub][2], z[3] * rl[sub][3] };
            *(float4*)(obase + (size_t)c * 1024 + t) = o;
        }
}

// ---------------- Fallback (single-kernel path, ws too small) ----------------
struct S1fb {
    _Float16 K[64][72];
    _Float16 V[64][72];
    _Float16 P[128][72];
};
union SMemFb {
    S1fb s1;
    float zt[64][132];
};

__launch_bounds__(256, 4)
__global__ void qkv_attn_fallback(const float* __restrict__ qkv,
                                  float* __restrict__ out) {
    constexpr int L = 1024;
    __shared__ SMemFb sm;
    const int tid  = threadIdx.x;
    const int wv   = tid >> 6;
    const int lane = tid & 63;
    const int li   = lane & 15;
    const int quad = lane >> 4;
    const int bid  = blockIdx.x;
    const int head = (bid >> 6) * 8 + (bid & 7);
    const int tt   = (bid >> 3) & 7;
    const int b = head >> 4;
    const int h = head & 15;
    const float* qbase = qkv + (size_t)b * 3072 * L + (size_t)(h * 64) * L;
    const float* kbase = qbase + (size_t)1024 * L;
    const float* vbase = qbase + (size_t)2048 * L;
    float*       obase = out + (size_t)b * 1024 * L + (size_t)(h * 64) * L;
    const int t0 = tt * 128;
#pragma unroll
    for (int i = 0; i < 4; ++i) {
        const int c = i * 16 + (tid >> 4);
        const int t = (tid & 15) * 8;
        const float4 qa = *(const float4*)(qbase + (size_t)c * L + t0 + t);
        const float4 qb = *(const float4*)(qbase + (size_t)c * L + t0 + t + 4);
        sm.s1.P[t + 0][c] = (_Float16)(qa.x * 0.125f);
        sm.s1.P[t + 1][c] = (_Float16)(qa.y * 0.125f);
        sm.s1.P[t + 2][c] = (_Float16)(qa.z * 0.125f);
        sm.s1.P[t + 3][c] = (_Float16)(qa.w * 0.125f);
        sm.s1.P[t + 4][c] = (_Float16)(qb.x * 0.125f);
        sm.s1.P[t + 5][c] = (_Float16)(qb.y * 0.125f);
        sm.s1.P[t + 6][c] = (_Float16)(qb.z * 0.125f);
        sm.s1.P[t + 7][c] = (_Float16)(qb.w * 0.125f);
    }
    __syncthreads();
    f16x8 aq0[2], aq1[2];
#pragma unroll
    for (int kk = 0; kk < 2; ++kk) {
        aq0[kk] = *(const f16x8*)&sm.s1.P[wv * 32 + li][kk * 32 + quad * 8];
        aq1[kk] = *(const f16x8*)&sm.s1.P[wv * 32 + 16 + li][kk * 32 + quad * 8];
    }
    f32x4 accz0[4] = {}, accz1[4] = {};
    float psum0[4] = {}, psum1[4] = {};
    float4 kreg[4], vreg[4];
#pragma unroll
    for (int i = 0; i < 4; ++i) {
        const int c = i * 16 + (tid >> 4);
        const int s = (tid & 15) * 4;
        kreg[i] = *(const float4*)(kbase + (size_t)c * L + s);
        vreg[i] = *(const float4*)(vbase + (size_t)c * L + s);
    }
    for (int si = 0; si < 16; ++si) {
        __syncthreads();
#pragma unroll
        for (int i = 0; i < 4; ++i) {
            const int c = i * 16 + (tid >> 4);
            const int s = (tid & 15) * 4;
            sm.s1.K[s + 0][c] = (_Float16)kreg[i].x;
            sm.s1.K[s + 1][c] = (_Float16)kreg[i].y;
            sm.s1.K[s + 2][c] = (_Float16)kreg[i].z;
            sm.s1.K[s + 3][c] = (_Float16)kreg[i].w;
            f16x4 pv = { (_Float16)vreg[i].x, (_Float16)vreg[i].y,
                         (_Float16)vreg[i].z, (_Float16)vreg[i].w };
            *(f16x4*)&sm.s1.V[c][s] = pv;
        }
        __syncthreads();
        if (si < 15) {
            const int s0n = (si + 1) * 64;
#pragma unroll
            for (int i = 0; i < 4; ++i) {
                const int c = i * 16 + (tid >> 4);
                const int s = (tid & 15) * 4;
                kreg[i] = *(const float4*)(kbase + (size_t)c * L + s0n + s);
                vreg[i] = *(const float4*)(vbase + (size_t)c * L + s0n + s);
            }
        }
#pragma unroll
        for (int nt = 0; nt < 4; ++nt) {
            f32x4 a0 = {}, a1 = {};
#pragma unroll
            for (int kk = 0; kk < 2; ++kk) {
                f16x8 bk = *(const f16x8*)&sm.s1.K[nt * 16 + li][kk * 32 + quad * 8];
                a0 = __builtin_amdgcn_mfma_f32_16x16x32_f16(aq0[kk], bk, a0, 0, 0, 0);
                a1 = __builtin_amdgcn_mfma_f32_16x16x32_f16(aq1[kk], bk, a1, 0, 0, 0);
            }
#pragma unroll
            for (int r = 0; r < 4; ++r) {
                const float p0 = __expf(a0[r]);
                const float p1 = __expf(a1[r]);
                psum0[r] += p0;
                psum1[r] += p1;
                sm.s1.P[wv * 32 + quad * 4 + r][nt * 16 + li] = (_Float16)p0;
                sm.s1.P[wv * 32 + 16 + quad * 4 + r][nt * 16 + li] = (_Float16)p1;
            }
        }
#pragma unroll
        for (int kk = 0; kk < 2; ++kk) {
            f16x8 ap0 = *(const f16x8*)&sm.s1.P[wv * 32 + li][kk * 32 + quad * 8];
            f16x8 ap1 = *(const f16x8*)&sm.s1.P[wv * 32 + 16 + li][kk * 32 + quad * 8];
#pragma unroll
            for (int nt = 0; nt < 4; ++nt) {
                f16x8 bv = *(const f16x8*)&sm.s1.V[nt * 16 + li][kk * 32 + quad * 8];
                accz0[nt] = __builtin_amdgcn_mfma_f32_16x16x32_f16(ap0, bv, accz0[nt], 0, 0, 0);
                accz1[nt] = __builtin_amdgcn_mfma_f32_16x16x32_f16(ap1, bv, accz1[nt], 0, 0, 0);
            }
        }
    }
    float rl0[4], rl1[4];
#pragma unroll
    for (int r = 0; r < 4; ++r) {
        float s0 = psum0[r], s1 = psum1[r];
        s0 += __shfl_xor(s0, 1); s0 += __shfl_xor(s0, 2);
        s0 += __shfl_xor(s0, 4); s0 += __shfl_xor(s0, 8);
        s1 += __shfl_xor(s1, 1); s1 += __shfl_xor(s1, 2);
        s1 += __shfl_xor(s1, 4); s1 += __shfl_xor(s1, 8);
        rl0[r] = 1.0f / s0;
        rl1[r] = 1.0f / s1;
    }
    __syncthreads();
#pragma unroll
    for (int nt = 0; nt < 4; ++nt)
#pragma unroll
        for (int r = 0; r < 4; ++r) {
            sm.zt[nt * 16 + li][wv * 32 + quad * 4 + r]      = accz0[nt][r] * rl0[r];
            sm.zt[nt * 16 + li][wv * 32 + 16 + quad * 4 + r] = accz1[nt][r] * rl1[r];
        }
    __syncthreads();
#pragma unroll
    for (int i = 0; i < 8; ++i) {
        const int c = i * 8 + (tid >> 5);
        const int t = (tid & 31) * 4;
        float4 o = { sm.zt[c][t], sm.zt[c][t + 1],
                     sm.zt[c][t + 2], sm.zt[c][t + 3] };
        *(float4*)(obase + (size_t)c * L + t0 + t) = o;
    }
}

extern "C" void kernel_launch(void* const* d_in, const int* in_sizes, int n_in,
                              void* d_out, int out_size, void* d_ws, size_t ws_size,
                              hipStream_t stream) {
    const float* qkv = (const float*)d_in[0];
    float* out = (float*)d_out;
    if (ws_size >= (size_t)WS_BYTES) {
        _Float16* ws = (_Float16*)d_ws;
        prepass_kv<<<4096, 256, 0, stream>>>(qkv, ws);
        // 128 heads x 4 t-tiles of 256; 512-thread blocks -> 2 blocks/CU, 16 waves
        attn_kernel<<<512, 512, 0, stream>>>(qkv, ws, out);
    } else {
        qkv_attn_fallback<<<1024, 256, 0, stream>>>(qkv, out);
    }
}

// Round 7
// 193.255 us; speedup vs baseline: 1.1896x; 1.0059x over previous
//
#include <hip/hip_runtime.h>

// QKVAttention: qkv [8, 3072, 1024] fp32 -> out [8, 1024, 1024] fp32
// Prepass: K (transpose+swizzle) and V (convert+swizzle) to fp16 ws.
// Attn: 256-thread blocks (4 waves x 64 t-rows, 4 subs/wave), t-tile 256.
// Rationale (r6 counters): MfmaUtil=VALUBusy=Occ=33% -> pipes serialized by
// wave phase-lock. 4 subs halves waves -> halves LDS traffic (K/V reads per
// wave are sub-count-independent) and gives 4 independent QK->exp->PV chains
// per wave; 256-thread blocks put 2 waves from DIFFERENT blocks on each SIMD
// (no shared barrier -> natural phase offset). Q fused via LDS-transpose
// prologue into separate ft array (prefetch of tiles 0/1 overlaps it).
// PV uses mfma_16x16x16 so the QK C-fragment feeds PV's A-operand directly.

typedef __attribute__((ext_vector_type(8))) _Float16 f16x8;
typedef __attribute__((ext_vector_type(4))) _Float16 f16x4;
typedef __attribute__((ext_vector_type(4))) float f32x4;

#define MAT_HALVES 8388608   // 16 MB per matrix (128 heads * 64 * 1024 halves)
#define WS_BYTES   33554432  // K + V fp16

#define ASYNC16(g, l) __builtin_amdgcn_global_load_lds(                    \
    (__attribute__((address_space(1))) void*)(void*)(g),                   \
    (__attribute__((address_space(3))) void*)(void*)(l), 16, 0, 0)

// ---------------- Pre-pass: K transpose + V convert, fp32 -> fp16 ------------
// Kt [head][s][64c], chunk c' = cb ^ (s&7)
// Vh [head][c][1024s], within each 64-s tile chunk s' = sb ^ (c&7)
__global__ __launch_bounds__(256) void prepass_kv(
    const float* __restrict__ qkv, _Float16* __restrict__ ws) {
    __shared__ float ft[64][68];
    const int tid = threadIdx.x;
    const int bid = blockIdx.x;       // 4096 = 2 mats * 128 heads * 16 blocks
    const int mat = bid >> 11;        // 0 K, 1 V
    const int idx = bid & 2047;
    const int head = idx >> 4;
    const int blk  = idx & 15;
    const int b = head >> 4, h = head & 15;
    const float* src = qkv + (size_t)b * 3072 * 1024
                           + (size_t)((1 + mat) * 1024 + h * 64) * 1024;
    const int s0 = blk * 64;
    if (mat == 0) {
#pragma unroll
        for (int i = 0; i < 4; ++i) {
            const int c = i * 16 + (tid >> 4);
            const int s = (tid & 15) * 4;
            const float4 v = *(const float4*)(src + (size_t)c * 1024 + s0 + s);
            ft[s + 0][c] = v.x;
            ft[s + 1][c] = v.y;
            ft[s + 2][c] = v.z;
            ft[s + 3][c] = v.w;
        }
        __syncthreads();
        _Float16* dst = ws + (size_t)head * 65536 + (size_t)s0 * 64;
#pragma unroll
        for (int r = 0; r < 2; ++r) {
            const int g = r * 256 + tid;
            const int t = g >> 3, cb = g & 7;
            const float4 a = *(const float4*)&ft[t][cb * 8];
            const float4 bq = *(const float4*)&ft[t][cb * 8 + 4];
            f16x8 o = { (_Float16)a.x,  (_Float16)a.y,  (_Float16)a.z,  (_Float16)a.w,
                        (_Float16)bq.x, (_Float16)bq.y, (_Float16)bq.z, (_Float16)bq.w };
            *(f16x8*)(dst + (size_t)t * 64 + (size_t)(cb ^ (t & 7)) * 8) = o;
        }
    } else {
        _Float16* dst = ws + (size_t)MAT_HALVES + (size_t)head * 65536;
#pragma unroll
        for (int i = 0; i < 4; ++i) {
            const int c = i * 16 + (tid >> 4);
            const int s = (tid & 15) * 4;
            const float4 v = *(const float4*)(src + (size_t)c * 1024 + s0 + s);
            f16x4 o = { (_Float16)v.x, (_Float16)v.y, (_Float16)v.z, (_Float16)v.w };
            const int sb = s >> 3, pos = s & 7;
            *(f16x4*)(dst + (size_t)c * 1024 + s0 + (size_t)((sb ^ (c & 7)) * 8 + pos)) = o;
        }
    }
}

// ---------------- Main flash kernel: 4 waves x 4 subs, dbuf K/V --------------
__launch_bounds__(256, 2)
__global__ void attn_kernel(const float* __restrict__ qkv,
                            const _Float16* __restrict__ ws,
                            float* __restrict__ out) {
    // kv[buf]: K [64 s][64 c] at halves 0..4095, V [64 c][64 s] at 4096..8191.
    __shared__ __align__(16) _Float16 kv[2][8192];   // 32 KB
    __shared__ __align__(16) float ft[64][68];       // 17 KB (prologue only)

    const int tid  = threadIdx.x;
    const int wv   = tid >> 6;        // 0..3
    const int lane = tid & 63;
    const int li   = lane & 15;
    const int quad = lane >> 4;

    const int bid  = blockIdx.x;
    const int head = (bid >> 5) * 8 + (bid & 7);  // head's 4 t-tiles share an XCD
    const int tt   = (bid >> 3) & 3;
    const int t0   = tt * 256;

    const int b = head >> 4, h = head & 15;
    const float* qsrc = qkv + (size_t)b * 3072 * 1024 + (size_t)(h * 64) * 1024;
    const _Float16* kt = ws + (size_t)head * 65536;
    const _Float16* vh = ws + (size_t)MAT_HALVES + (size_t)head * 65536;

    // ---- Prefetch tiles 0,1 into kv[0],kv[1] (overlaps Q prologue) ----
#pragma unroll
    for (int u = 0; u < 2; ++u) {
        const int s0 = u * 64;
#pragma unroll
        for (int j = 0; j < 2; ++j) {
            const int g = j * 256 + tid;
            ASYNC16(kt + (size_t)s0 * 64 + (size_t)g * 8, &kv[u][g * 8]);
            ASYNC16(vh + (size_t)(g >> 3) * 1024 + s0 + (size_t)(g & 7) * 8,
                    &kv[u][4096 + g * 8]);
        }
    }

    // ---- Q prologue: 4 chunks of 64 t, fp32 LDS transpose -> bqf regs ----
    const float qscale = 0.125f * 1.44269504f;
    f16x8 bqf[4][2];
    for (int ct = 0; ct < 4; ++ct) {
#pragma unroll
        for (int i = 0; i < 4; ++i) {
            const int c = i * 16 + (tid >> 4);
            const int t = (tid & 15) * 4;
            const float4 v = *(const float4*)(qsrc + (size_t)c * 1024 + t0 + ct * 64 + t);
            ft[t + 0][c] = v.x * qscale;
            ft[t + 1][c] = v.y * qscale;
            ft[t + 2][c] = v.z * qscale;
            ft[t + 3][c] = v.w * qscale;
        }
        __syncthreads();
        if (wv == ct) {
#pragma unroll
            for (int sub = 0; sub < 4; ++sub) {
                const int tl = sub * 16 + li;
#pragma unroll
                for (int kk = 0; kk < 2; ++kk) {
                    const int c0 = (kk * 4 + quad) * 8;
                    const float4 a  = *(const float4*)&ft[tl][c0];
                    const float4 b2 = *(const float4*)&ft[tl][c0 + 4];
                    bqf[sub][kk] = f16x8{ (_Float16)a.x,  (_Float16)a.y,
                                          (_Float16)a.z,  (_Float16)a.w,
                                          (_Float16)b2.x, (_Float16)b2.y,
                                          (_Float16)b2.z, (_Float16)b2.w };
                }
            }
        }
        __syncthreads();
    }

    f32x4 accz[4][4] = {};       // [sub][nc]
    float psum[4] = {};

    // ---- Main loop: 16 s-tiles, dbuf, 1 barrier/iter, prefetch after ----
    for (int si = 0; si < 16; ++si) {
        __syncthreads();  // buf[si&1] loads drained; prior reads of other buf done
        if (si < 15) {
            const int s0n = (si + 1) * 64;
            const int nb = (si + 1) & 1;
#pragma unroll
            for (int j = 0; j < 2; ++j) {
                const int g = j * 256 + tid;
                ASYNC16(kt + (size_t)s0n * 64 + (size_t)g * 8, &kv[nb][g * 8]);
                ASYNC16(vh + (size_t)(g >> 3) * 1024 + s0n + (size_t)(g & 7) * 8,
                        &kv[nb][4096 + g * 8]);
            }
        }
        const _Float16* Kl = &kv[si & 1][0];
        const _Float16* Vl = &kv[si & 1][4096];

        __builtin_amdgcn_s_setprio(1);
#pragma unroll
        for (int ns = 0; ns < 4; ++ns) {
            // S^T = K Q^T for this 16-s strip (k=64 via 2 x mfma 16x16x32)
            f16x8 ak[2];
#pragma unroll
            for (int kk = 0; kk < 2; ++kk) {
                const int cb = (kk * 4 + quad) ^ (li & 7);
                ak[kk] = *(const f16x8*)&Kl[(ns * 16 + li) * 64 + cb * 8];
            }
            f16x4 pk[4];
#pragma unroll
            for (int sub = 0; sub < 4; ++sub) {
                f32x4 st = {};
                st = __builtin_amdgcn_mfma_f32_16x16x32_f16(ak[0], bqf[sub][0], st, 0, 0, 0);
                st = __builtin_amdgcn_mfma_f32_16x16x32_f16(ak[1], bqf[sub][1], st, 0, 0, 0);
                const float p0 = __builtin_amdgcn_exp2f(st[0]);
                const float p1 = __builtin_amdgcn_exp2f(st[1]);
                const float p2 = __builtin_amdgcn_exp2f(st[2]);
                const float p3 = __builtin_amdgcn_exp2f(st[3]);
                psum[sub] += (p0 + p1) + (p2 + p3);
                pk[sub] = f16x4{ (_Float16)p0, (_Float16)p1,
                                 (_Float16)p2, (_Float16)p3 };
            }
            // Z^T += P V^T for this strip: pk IS the 16x16x16 A-operand.
            const int sb  = 2 * ns + (quad >> 1);
            const int pos = (quad & 1) * 4;
#pragma unroll
            for (int nc = 0; nc < 4; ++nc) {
                const int c = nc * 16 + li;
                f16x4 bv = *(const f16x4*)&Vl[c * 64 + ((sb ^ (c & 7)) << 3) + pos];
#pragma unroll
                for (int sub = 0; sub < 4; ++sub)
                    accz[sub][nc] = __builtin_amdgcn_mfma_f32_16x16x16f16(
                        pk[sub], bv, accz[sub][nc], 0, 0, 0);
            }
        }
        __builtin_amdgcn_s_setprio(0);
    }

    // ---- Denominators: cross-quad reduce + redistribute ----
    float rl[4][4];
#pragma unroll
    for (int sub = 0; sub < 4; ++sub) {
        float s = psum[sub];
        s += __shfl_xor(s, 16);
        s += __shfl_xor(s, 32);
#pragma unroll
        for (int r = 0; r < 4; ++r)
            rl[sub][r] = 1.0f / __shfl(s, quad * 4 + r);
    }

    // ---- Store: D^T rows contiguous in t -> direct float4 stores ----
    float* obase = out + (size_t)b * 1024 * 1024
                       + (size_t)(h * 64) * 1024 + t0;
#pragma unroll
    for (int sub = 0; sub < 4; ++sub)
#pragma unroll
        for (int nc = 0; nc < 4; ++nc) {
            const int c = nc * 16 + li;
            const int t = wv * 64 + sub * 16 + quad * 4;
            f32x4 z = accz[sub][nc];
            float4 o = { z[0] * rl[sub][0], z[1] * rl[sub][1],
                         z[2] * rl[sub][2], z[3] * rl[sub][3] };
            *(float4*)(obase + (size_t)c * 1024 + t) = o;
        }
}

// ---------------- Fallback (single-kernel path, ws too small) ----------------
struct S1fb {
    _Float16 K[64][72];
    _Float16 V[64][72];
    _Float16 P[128][72];
};
union SMemFb {
    S1fb s1;
    float zt[64][132];
};

__launch_bounds__(256, 4)
__global__ void qkv_attn_fallback(const float* __restrict__ qkv,
                                  float* __restrict__ out) {
    constexpr int L = 1024;
    __shared__ SMemFb sm;
    const int tid  = threadIdx.x;
    const int wv   = tid >> 6;
    const int lane = tid & 63;
    const int li   = lane & 15;
    const int quad = lane >> 4;
    const int bid  = blockIdx.x;
    const int head = (bid >> 6) * 8 + (bid & 7);
    const int tt   = (bid >> 3) & 7;
    const int b = head >> 4;
    const int h = head & 15;
    const float* qbase = qkv + (size_t)b * 3072 * L + (size_t)(h * 64) * L;
    const float* kbase = qbase + (size_t)1024 * L;
    const float* vbase = qbase + (size_t)2048 * L;
    float*       obase = out + (size_t)b * 1024 * L + (size_t)(h * 64) * L;
    const int t0 = tt * 128;
#pragma unroll
    for (int i = 0; i < 4; ++i) {
        const int c = i * 16 + (tid >> 4);
        const int t = (tid & 15) * 8;
        const float4 qa = *(const float4*)(qbase + (size_t)c * L + t0 + t);
        const float4 qb = *(const float4*)(qbase + (size_t)c * L + t0 + t + 4);
        sm.s1.P[t + 0][c] = (_Float16)(qa.x * 0.125f);
        sm.s1.P[t + 1][c] = (_Float16)(qa.y * 0.125f);
        sm.s1.P[t + 2][c] = (_Float16)(qa.z * 0.125f);
        sm.s1.P[t + 3][c] = (_Float16)(qa.w * 0.125f);
        sm.s1.P[t + 4][c] = (_Float16)(qb.x * 0.125f);
        sm.s1.P[t + 5][c] = (_Float16)(qb.y * 0.125f);
        sm.s1.P[t + 6][c] = (_Float16)(qb.z * 0.125f);
        sm.s1.P[t + 7][c] = (_Float16)(qb.w * 0.125f);
    }
    __syncthreads();
    f16x8 aq0[2], aq1[2];
#pragma unroll
    for (int kk = 0; kk < 2; ++kk) {
        aq0[kk] = *(const f16x8*)&sm.s1.P[wv * 32 + li][kk * 32 + quad * 8];
        aq1[kk] = *(const f16x8*)&sm.s1.P[wv * 32 + 16 + li][kk * 32 + quad * 8];
    }
    f32x4 accz0[4] = {}, accz1[4] = {};
    float psum0[4] = {}, psum1[4] = {};
    float4 kreg[4], vreg[4];
#pragma unroll
    for (int i = 0; i < 4; ++i) {
        const int c = i * 16 + (tid >> 4);
        const int s = (tid & 15) * 4;
        kreg[i] = *(const float4*)(kbase + (size_t)c * L + s);
        vreg[i] = *(const float4*)(vbase + (size_t)c * L + s);
    }
    for (int si = 0; si < 16; ++si) {
        __syncthreads();
#pragma unroll
        for (int i = 0; i < 4; ++i) {
            const int c = i * 16 + (tid >> 4);
            const int s = (tid & 15) * 4;
            sm.s1.K[s + 0][c] = (_Float16)kreg[i].x;
            sm.s1.K[s + 1][c] = (_Float16)kreg[i].y;
            sm.s1.K[s + 2][c] = (_Float16)kreg[i].z;
            sm.s1.K[s + 3][c] = (_Float16)kreg[i].w;
            f16x4 pv = { (_Float16)vreg[i].x, (_Float16)vreg[i].y,
                         (_Float16)vreg[i].z, (_Float16)vreg[i].w };
            *(f16x4*)&sm.s1.V[c][s] = pv;
        }
        __syncthreads();
        if (si < 15) {
            const int s0n = (si + 1) * 64;
#pragma unroll
            for (int i = 0; i < 4; ++i) {
                const int c = i * 16 + (tid >> 4);
                const int s = (tid & 15) * 4;
                kreg[i] = *(const float4*)(kbase + (size_t)c * L + s0n + s);
                vreg[i] = *(const float4*)(vbase + (size_t)c * L + s0n + s);
            }
        }
#pragma unroll
        for (int nt = 0; nt < 4; ++nt) {
            f32x4 a0 = {}, a1 = {};
#pragma unroll
            for (int kk = 0; kk < 2; ++kk) {
                f16x8 bk = *(const f16x8*)&sm.s1.K[nt * 16 + li][kk * 32 + quad * 8];
                a0 = __builtin_amdgcn_mfma_f32_16x16x32_f16(aq0[kk], bk, a0, 0, 0, 0);
                a1 = __builtin_amdgcn_mfma_f32_16x16x32_f16(aq1[kk], bk, a1, 0, 0, 0);
            }
#pragma unroll
            for (int r = 0; r < 4; ++r) {
                const float p0 = __expf(a0[r]);
                const float p1 = __expf(a1[r]);
                psum0[r] += p0;
                psum1[r] += p1;
                sm.s1.P[wv * 32 + quad * 4 + r][nt * 16 + li] = (_Float16)p0;
                sm.s1.P[wv * 32 + 16 + quad * 4 + r][nt * 16 + li] = (_Float16)p1;
            }
        }
#pragma unroll
        for (int kk = 0; kk < 2; ++kk) {
            f16x8 ap0 = *(const f16x8*)&sm.s1.P[wv * 32 + li][kk * 32 + quad * 8];
            f16x8 ap1 = *(const f16x8*)&sm.s1.P[wv * 32 + 16 + li][kk * 32 + quad * 8];
#pragma unroll
            for (int nt = 0; nt < 4; ++nt) {
                f16x8 bv = *(const f16x8*)&sm.s1.V[nt * 16 + li][kk * 32 + quad * 8];
                accz0[nt] = __builtin_amdgcn_mfma_f32_16x16x32_f16(ap0, bv, accz0[nt], 0, 0, 0);
                accz1[nt] = __builtin_amdgcn_mfma_f32_16x16x32_f16(ap1, bv, accz1[nt], 0, 0, 0);
            }
        }
    }
    float rl0[4], rl1[4];
#pragma unroll
    for (int r = 0; r < 4; ++r) {
        float s0 = psum0[r], s1 = psum1[r];
        s0 += __shfl_xor(s0, 1); s0 += __shfl_xor(s0, 2);
        s0 += __shfl_xor(s0, 4); s0 += __shfl_xor(s0, 8);
        s1 += __shfl_xor(s1, 1); s1 += __shfl_xor(s1, 2);
        s1 += __shfl_xor(s1, 4); s1 += __shfl_xor(s1, 8);
        rl0[r] = 1.0f / s0;
        rl1[r] = 1.0f / s1;
    }
    __syncthreads();
#pragma unroll
    for (int nt = 0; nt < 4; ++nt)
#pragma unroll
        for (int r = 0; r < 4; ++r) {
            sm.zt[nt * 16 + li][wv * 32 + quad * 4 + r]      = accz0[nt][r] * rl0[r];
            sm.zt[nt * 16 + li][wv * 32 + 16 + quad * 4 + r] = accz1[nt][r] * rl1[r];
        }
    __syncthreads();
#pragma unroll
    for (int i = 0; i < 8; ++i) {
        const int c = i * 8 + (tid >> 5);
        const int t = (tid & 31) * 4;
        float4 o = { sm.zt[c][t], sm.zt[c][t + 1],
                     sm.zt[c][t + 2], sm.zt[c][t + 3] };
        *(float4*)(obase + (size_t)c * L + t0 + t) = o;
    }
}

extern "C" void kernel_launch(void* const* d_in, const int* in_sizes, int n_in,
                              void* d_out, int out_size, void* d_ws, size_t ws_size,
                              hipStream_t stream) {
    const float* qkv = (const float*)d_in[0];
    float* out = (float*)d_out;
    if (ws_size >= (size_t)WS_BYTES) {
        _Float16* ws = (_Float16*)d_ws;
        prepass_kv<<<4096, 256, 0, stream>>>(qkv, ws);
        // 128 heads x 4 t-tiles of 256; 256-thread blocks -> 2 blocks/CU,
        // 8 waves/CU, SIMD hosts waves from DIFFERENT blocks (desync).
        attn_kernel<<<512, 256, 0, stream>>>(qkv, ws, out);
    } else {
        qkv_attn_fallback<<<1024, 256, 0, stream>>>(qkv, out);
    }
}